// Round 9
// baseline (449.655 us; speedup 1.0000x reference)
//
#include <hip/hip_runtime.h>

typedef _Float16 f16;
typedef __attribute__((ext_vector_type(8))) _Float16 half8;   // MFMA A/B frag (4 VGPRs)
typedef __attribute__((ext_vector_type(4))) _Float16 half4;
typedef __attribute__((ext_vector_type(4))) float   f4;       // MFMA C/D

#define NTOK   196
#define MROWS  50176            // 256 * 196
#define HIDN   1536
#define HPC    192              // per-head channels in h (q32|k32|v128)
#define DHD    1024             // H * 128
#define EPSV   1e-5f
// SCALEV * log2(e): softmax computed in exp2 domain (bias table also pre-scaled)
#define SCALE2 0.25503524f
#define LOG2E  1.4426950408889634f

// async global->LDS, 16B per lane; LDS dest is wave-uniform base + lane*16
#define GLD16(gp, lp) __builtin_amdgcn_global_load_lds( \
    (const __attribute__((address_space(1))) unsigned int*)(gp), \
    (__attribute__((address_space(3))) unsigned int*)(lp), 16, 0, 0)

// rotation swizzle: spreads banks for reads (row bits 0-3) AND writes (row bits 3-5)
__device__ inline int swz8(int row) { return (((row & 7) ^ ((row >> 3) & 7))) * 8; }

// ---------------- f32 -> f16 convert (vectorized)
__global__ void cvt_f32_f16(const float* __restrict__ src, f16* __restrict__ dst, int n4)
{
    int i = blockIdx.x * blockDim.x + threadIdx.x;
    if (i < n4) {
        float4 v = *(const float4*)&src[i * 4];
        half4 h = { (f16)v.x, (f16)v.y, (f16)v.z, (f16)v.w };
        *(half4*)&dst[i * 4] = h;
    }
}

// ---------------- bias_full[h][208][224] f16, PRE-SCALED by log2(e) for exp2-domain
// softmax; idxs gather resolved once; pad = -30000*log2e (mask baked in)
__global__ void build_bias(const float* __restrict__ bt, const int* __restrict__ idxs,
                           f16* __restrict__ bf)
{
    int i = blockIdx.x * 256 + threadIdx.x;
    if (i >= 8 * 208 * 224) return;
    int k = i % 224, q = (i / 224) % 208, h = i / (224 * 208);
    float v = -30000.f;
    if (q < NTOK && k < NTOK) v = bt[h * NTOK + idxs[q * NTOK + k]];
    bf[i] = (f16)(v * LOG2E);
}

// ---- shared pipeline body for both GEMMs ----
// Race-freedom proof: (a) each wave executes lgkmcnt(0) AFTER its ds_reads and
// BEFORE the next body's s_barrier -> reads complete before any wave passes that
// barrier; (b) the GLD that overwrites buf[(ST+2)%3] (last read at body ST-1) is
// issued AFTER that barrier -> its LDS write lands after all reads. (c) vmcnt
// gate "4" at body top: the 4 newest outstanding loads are body (ST-1)'s group
// (for step ST+1); everything older -- including step ST's group -- has retired
// (vmcnt retires in order). Distinct named buffers keep alias analysis exact so
// the compiler inserts no spurious serializing waits (v6 lesson).
// setprio kept HERE only: helps counted-vmcnt phase-split GEMM schedules (m218b);
// removed from attn where it starved co-resident waves (v10 regression).
#define PIPE_BODY(CA, CB, PA, PB, ST, HASPF, GATE)                              \
  {                                                                             \
    asm volatile("s_waitcnt vmcnt(" GATE ")" ::: "memory");                     \
    __builtin_amdgcn_s_barrier();                                               \
    __builtin_amdgcn_sched_barrier(0);                                          \
    if (HASPF) {                                                                \
      const f16* Apf_ = Ab + ((ST) + 2) * 32;                                   \
      const f16* Bpf_ = Bb + ((ST) + 2) * 32;                                   \
      GLD16(Apf_,          &PA[so0]);                                           \
      GLD16(Apf_ + 16 * K, &PA[so1]);                                           \
      GLD16(Bpf_,          &PB[so0]);                                           \
      GLD16(Bpf_ + 16 * K, &PB[so1]);                                           \
    }                                                                           \
    half8 a_[4], b_[4];                                                         \
    _Pragma("unroll")                                                           \
    for (int i_ = 0; i_ < 4; ++i_) {                                            \
      a_[i_] = *(const half8*)&CA[(wm + i_ * 16 + lm) * 32 + rs];               \
      b_[i_] = *(const half8*)&CB[(wn + i_ * 16 + lm) * 32 + rs];               \
    }                                                                           \
    asm volatile("s_waitcnt lgkmcnt(0)" ::: "memory");                          \
    __builtin_amdgcn_sched_barrier(0);                                          \
    __builtin_amdgcn_s_setprio(1);                                              \
    _Pragma("unroll")                                                           \
    for (int i_ = 0; i_ < 4; ++i_)                                              \
      _Pragma("unroll")                                                         \
      for (int j_ = 0; j_ < 4; ++j_)                                            \
        acc[i_][j_] = __builtin_amdgcn_mfma_f32_16x16x32_f16(                   \
            a_[i_], b_[j_], acc[i_][j_], 0, 0, 0);                              \
    __builtin_amdgcn_s_setprio(0);                                              \
  }

// ---------------- GEMM1: h = x @ Wqkv^T  (f16 in, f16 out + BN stats)
// v9: 3-buffer counted-vmcnt pipeline (distinct arrays, explicit lgkm0 fence).
// Staging source pre-swizzle (chunk ^= row&3) + matching read offset breaks the
// per-quad LDS bank clustering.
__global__ __launch_bounds__(256) void gemm1_qkv(
    const f16* __restrict__ A, const f16* __restrict__ B,
    f16* __restrict__ C, float* __restrict__ gsum, float* __restrict__ gsq)
{
    const int K = 256, ldc = HIDN;
    __shared__ f16 As0[4096], As1[4096], As2[4096];
    __shared__ f16 Bs0[4096], Bs1[4096], Bs2[4096];
    __shared__ float ssum[128], ssq[128];

    const int t = threadIdx.x;
    const int m0 = blockIdx.x * 128, n0 = blockIdx.y * 128;
    const int wid = t >> 6, lane = t & 63, quad = lane >> 4, lm = lane & 15;
    const int wm = (wid >> 1) * 64, wn = (wid & 1) * 64;

    // staging: wave w slot s covers rows w*32+s*16.. (lane>>2); 16B chunk pre-swizzled
    const int lr = lane >> 2;
    const int lc = ((lane & 3) ^ (lr & 3)) * 8;        // global chunk XOR row&3
    const int so0 = (wid * 2 + 0) * 512, so1 = (wid * 2 + 1) * 512;
    const f16* Ab = A + (long)(m0 + wid * 32 + lr) * K + lc;
    const f16* Bb = B + (long)(n0 + wid * 32 + lr) * K + lc;
    const int rs = (quad ^ (lm & 3)) * 8;              // read-side XOR (row&3 == lm&3)

    f4 acc[4][4] = {};

    // prologue: stage K-steps 0 and 1
    GLD16(Ab,               &As0[so0]);
    GLD16(Ab + 16 * K,      &As0[so1]);
    GLD16(Bb,               &Bs0[so0]);
    GLD16(Bb + 16 * K,      &Bs0[so1]);
    GLD16(Ab + 32,          &As1[so0]);
    GLD16(Ab + 16 * K + 32, &As1[so1]);
    GLD16(Bb + 32,          &Bs1[so0]);
    GLD16(Bb + 16 * K + 32, &Bs1[so1]);

    // 8 K-steps, buffer = step % 3
    PIPE_BODY(As0, Bs0, As2, Bs2, 0, 1, "4");
    PIPE_BODY(As1, Bs1, As0, Bs0, 1, 1, "4");
    PIPE_BODY(As2, Bs2, As1, Bs1, 2, 1, "4");
    PIPE_BODY(As0, Bs0, As2, Bs2, 3, 1, "4");
    PIPE_BODY(As1, Bs1, As0, Bs0, 4, 1, "4");
    PIPE_BODY(As2, Bs2, As1, Bs1, 5, 1, "4");
    PIPE_BODY(As0, Bs0, As2, Bs2, 6, 0, "4");
    PIPE_BODY(As1, Bs1, As0, Bs0, 7, 0, "0");

    __syncthreads();
    if (t < 128) { ssum[t] = 0.f; ssq[t] = 0.f; }
    __syncthreads();

    #pragma unroll
    for (int j = 0; j < 4; ++j) {
        int nl = wn + j*16 + lm;
        float psum = 0.f, psq = 0.f;
        #pragma unroll
        for (int i = 0; i < 4; ++i) {
            #pragma unroll
            for (int r = 0; r < 4; ++r) {
                int ml = wm + i*16 + quad*4 + r;
                float v = acc[i][j][r];
                f16 uh = (f16)v;
                float vb = (float)uh;
                C[(long)(m0 + ml) * ldc + n0 + nl] = uh;
                psum += vb; psq += vb * vb;
            }
        }
        atomicAdd(&ssum[nl], psum);
        atomicAdd(&ssq[nl], psq);
    }
    __syncthreads();
    if (t < 128) {
        atomicAdd(&gsum[n0 + t], ssum[t]);
        atomicAdd(&gsq[n0 + t],  ssq[t]);
    }
}

// ---------------- GEMM2: p = o @ Wproj^T  (f16 in, f32 out + BN stats)
// v9: same 3-buffer pipeline; 32 K-steps = 5 x 6-body chunks + 2-body tail.
__global__ __launch_bounds__(256) void gemm2_proj(
    const f16* __restrict__ A, const f16* __restrict__ B,
    float* __restrict__ C, float* __restrict__ gsum, float* __restrict__ gsq)
{
    const int K = 1024, ldc = 256;
    __shared__ f16 As0[4096], As1[4096], As2[4096];
    __shared__ f16 Bs0[4096], Bs1[4096], Bs2[4096];
    __shared__ float ssum[128], ssq[128];

    const int t = threadIdx.x;
    const int m0 = blockIdx.x * 128, n0 = blockIdx.y * 128;
    const int wid = t >> 6, lane = t & 63, quad = lane >> 4, lm = lane & 15;
    const int wm = (wid >> 1) * 64, wn = (wid & 1) * 64;

    const int lr = lane >> 2;
    const int lc = ((lane & 3) ^ (lr & 3)) * 8;
    const int so0 = (wid * 2 + 0) * 512, so1 = (wid * 2 + 1) * 512;
    const f16* Ab = A + (long)(m0 + wid * 32 + lr) * K + lc;
    const f16* Bb = B + (long)(n0 + wid * 32 + lr) * K + lc;
    const int rs = (quad ^ (lm & 3)) * 8;

    f4 acc[4][4] = {};

    GLD16(Ab,               &As0[so0]);
    GLD16(Ab + 16 * K,      &As0[so1]);
    GLD16(Bb,               &Bs0[so0]);
    GLD16(Bb + 16 * K,      &Bs0[so1]);
    GLD16(Ab + 32,          &As1[so0]);
    GLD16(Ab + 16 * K + 32, &As1[so1]);
    GLD16(Bb + 32,          &Bs1[so0]);
    GLD16(Bb + 16 * K + 32, &Bs1[so1]);

    for (int s = 0; s < 30; s += 6) {
        PIPE_BODY(As0, Bs0, As2, Bs2, s + 0, 1, "4");
        PIPE_BODY(As1, Bs1, As0, Bs0, s + 1, 1, "4");
        PIPE_BODY(As2, Bs2, As1, Bs1, s + 2, 1, "4");
        PIPE_BODY(As0, Bs0, As2, Bs2, s + 3, 1, "4");
        PIPE_BODY(As1, Bs1, As0, Bs0, s + 4, 1, "4");
        PIPE_BODY(As2, Bs2, As1, Bs1, s + 5, 1, "4");
    }
    PIPE_BODY(As0, Bs0, As2, Bs2, 30, 0, "4");
    PIPE_BODY(As1, Bs1, As0, Bs0, 31, 0, "0");

    __syncthreads();
    if (t < 128) { ssum[t] = 0.f; ssq[t] = 0.f; }
    __syncthreads();

    #pragma unroll
    for (int j = 0; j < 4; ++j) {
        int nl = wn + j*16 + lm;
        float psum = 0.f, psq = 0.f;
        #pragma unroll
        for (int i = 0; i < 4; ++i) {
            #pragma unroll
            for (int r = 0; r < 4; ++r) {
                int ml = wm + i*16 + quad*4 + r;
                float v = acc[i][j][r];
                C[(long)(m0 + ml) * ldc + n0 + nl] = v;
                psum += v; psq += v * v;
            }
        }
        atomicAdd(&ssum[nl], psum);
        atomicAdd(&ssq[nl], psq);
    }
    __syncthreads();
    if (t < 128) {
        atomicAdd(&gsum[n0 + t], ssum[t]);
        atomicAdd(&gsq[n0 + t],  ssq[t]);
    }
}

__global__ void bn_fin(const float* __restrict__ gsum, const float* __restrict__ gsq,
                       const float* __restrict__ g, const float* __restrict__ b,
                       float* __restrict__ a_out, float* __restrict__ s_out, int nch)
{
    int c = blockIdx.x * blockDim.x + threadIdx.x;
    if (c >= nch) return;
    float inv  = 1.f / (float)MROWS;
    float mean = gsum[c] * inv;
    float var  = gsq[c] * inv - mean * mean;
    float a    = g[c] * rsqrtf(var + EPSV);
    a_out[c] = a;
    s_out[c] = b[c] - mean * a;
}

// ---------------- attention: one block (13 waves, 832 threads) per (batch, head).
// v11: v10 minus setprio (it preferred the MFMA-latency-stalled wave and starved
// co-resident waves -> 131->142 regression), plus dual-accumulator PV (even/odd nt)
// to halve the dependent-MFMA chain. Packed-f16 affine + exp2-domain softmax kept.
__global__ __launch_bounds__(832) void attn_kernel(
    const f16* __restrict__ hbuf, const float* __restrict__ a1, const float* __restrict__ s1,
    const f16* __restrict__ bf, f16* __restrict__ obuf)
{
    __shared__ f16 ks[208][32];
    __shared__ f16 vT[128][256];
    __shared__ f16 afh[192], sfh[192];

    const int t  = threadIdx.x;
    const int bb = blockIdx.x >> 3;
    const int hh = blockIdx.x & 7;
    const int wid = t >> 6, lane = t & 63, quad = lane >> 4, lm = lane & 15;

    if (t < 192) { afh[t] = (f16)a1[hh * HPC + t]; sfh[t] = (f16)s1[hh * HPC + t]; }
    half8 z8 = {};
    for (int i = t; i < 4096; i += 832) *(half8*)&vT[i >> 5][(i & 31) * 8] = z8;
    if (t < 384) ks[196 + (t >> 5)][t & 31] = (f16)0.f;
    __syncthreads();

    // stage k/v (channels 32..191) with packed-f16 BN1 affine, rotation-swizzled
    {
        int t8 = t & 7;
        for (int rr = t >> 3; rr < NTOK; rr += 104) {
            const f16* hrow = hbuf + (long)(bb * NTOK + rr) * HIDN + hh * HPC;
            int sr = swz8(rr);
            #pragma unroll
            for (int cc = 0; cc < 3; ++cc) {
                int cb = 32 + (t8 + cc * 8) * 8;   // 32..216 step 8; skip >=192
                if (cb >= 192) continue;
                half8 raw = *(const half8*)(hrow + cb);
                half8 a8  = *(const half8*)&afh[cb];
                half8 s8  = *(const half8*)&sfh[cb];
                half8 ov  = raw * a8 + s8;          // v_pk_fma_f16 x4
                if (cb < 64) {
                    // rotation start (cb-32+sr)&31 is a multiple of 8 -> contiguous, no wrap
                    *(half8*)&ks[rr][(cb - 32 + sr) & 31] = ov;
                } else {
                    #pragma unroll
                    for (int e = 0; e < 8; ++e) {
                        int c = cb - 64 + e;
                        vT[c][(rr + swz8(c)) & 255] = ov[e];
                    }
                }
            }
        }
    }
    __syncthreads();

    const int mt = wid;                                  // one tile per wave, 13 waves
    const int qrow = mt * 16 + lm;                       // 0..207 (>=196 masked rows)
    const f16* bfh = bf + hh * 208 * 224;

    // ---- q B-frag direct from global + packed f16 BN1 affine (q = channels 0..31)
    long grow = (long)bb * NTOK + qrow;
    if (grow > (long)(MROWS - 1)) grow = MROWS - 1;      // clamp tail OOB (values masked)
    half8 qraw = *(const half8*)(hbuf + grow * HIDN + hh * HPC + quad * 8);
    half8 qa = *(const half8*)&afh[quad * 8];
    half8 qs = *(const half8*)&sfh[quad * 8];
    half8 qf = qraw * qa + qs;

    // ---- S^T = K·Q^T (13 MFMAs). Lane holds q = qrow (col=lm), k = nt*16 + quad*4 + r.
    f4 sreg[13];
    #pragma unroll
    for (int nt = 0; nt < 13; ++nt) {
        int krow = nt * 16 + lm;
        half8 ak = *(const half8*)&ks[krow][(quad * 8 + swz8(krow)) & 31];
        f4 z = {};
        sreg[nt] = __builtin_amdgcn_mfma_f32_16x16x32_f16(ak, qf, z, 0, 0, 0);
    }

    // ---- scale + bias in exp2 domain (mask baked into bias pad), running max
    const f16* brow = bfh + qrow * 224 + quad * 4;
    float m = -3.0e38f;
    #pragma unroll
    for (int nt = 0; nt < 13; ++nt) {
        half4 b4 = *(const half4*)(brow + nt * 16);
        #pragma unroll
        for (int r = 0; r < 4; ++r) {
            sreg[nt][r] = fmaf(sreg[nt][r], SCALE2, (float)b4[r]);
            m = fmaxf(m, sreg[nt][r]);
        }
    }
    m = fmaxf(m, __shfl_xor(m, 16));
    m = fmaxf(m, __shfl_xor(m, 32));

    // ---- exp2 + sum; P stays unnormalized (<=1) f16 in regs as PV A-frags
    float s = 0.f;
    half4 ap[13];
    #pragma unroll
    for (int nt = 0; nt < 13; ++nt) {
        float e0 = exp2f(sreg[nt][0] - m);
        float e1 = exp2f(sreg[nt][1] - m);
        float e2 = exp2f(sreg[nt][2] - m);
        float e3 = exp2f(sreg[nt][3] - m);
        s += (e0 + e1) + (e2 + e3);
        ap[nt] = half4{ (f16)e0, (f16)e1, (f16)e2, (f16)e3 };
    }
    s += __shfl_xor(s, 16);
    s += __shfl_xor(s, 32);
    float rinv = 1.f / s;

    // redistribute rinv to output layout (row = quad*4+r)
    float rv[4];
    #pragma unroll
    for (int r = 0; r < 4; ++r) rv[r] = __shfl(rinv, quad * 4 + r);

    // ---- O = P·V via 16x16x16; dual accumulators break the dependent MFMA chain
    #pragma unroll
    for (int ct = 0; ct < 8; ++ct) {
        int c = ct * 16 + lm;
        int sc = swz8(c);
        f4 oa0 = {}, oa1 = {};
        #pragma unroll
        for (int nt = 0; nt < 12; nt += 2) {
            half4 bv0 = *(const half4*)&vT[c][((nt + 0) * 16 + quad * 4 + sc) & 255];
            half4 bv1 = *(const half4*)&vT[c][((nt + 1) * 16 + quad * 4 + sc) & 255];
            oa0 = __builtin_amdgcn_mfma_f32_16x16x16f16(ap[nt + 0], bv0, oa0, 0, 0, 0);
            oa1 = __builtin_amdgcn_mfma_f32_16x16x16f16(ap[nt + 1], bv1, oa1, 0, 0, 0);
        }
        {
            half4 bv12 = *(const half4*)&vT[c][(12 * 16 + quad * 4 + sc) & 255];
            oa0 = __builtin_amdgcn_mfma_f32_16x16x16f16(ap[12], bv12, oa0, 0, 0, 0);
        }
        #pragma unroll
        for (int r = 0; r < 4; ++r) {
            int qr = mt * 16 + quad * 4 + r;
            if (qr < 196) {
                float v  = (oa0[r] + oa1[r]) * rv[r];
                float hs = v * fminf(fmaxf(v + 3.f, 0.f), 6.f) * (1.f / 6.f);
                obuf[(long)(bb * NTOK + qr) * DHD + hh * 128 + c] = (f16)hs;
            }
        }
    }
}

__global__ __launch_bounds__(256) void bn_apply(
    float* __restrict__ out, const float* __restrict__ a2, const float* __restrict__ s2)
{
    __shared__ float aL[256], sL[256];
    int t = threadIdx.x;
    aL[t] = a2[t]; sL[t] = s2[t];
    __syncthreads();
    long total = (long)MROWS * 256 / 4;
    for (long i = (long)blockIdx.x * 256 + t; i < total; i += (long)gridDim.x * 256) {
        float4 v = *(float4*)&out[i * 4];
        int cb = (int)((i * 4) & 255);
        v.x = v.x * aL[cb + 0] + sL[cb + 0];
        v.y = v.y * aL[cb + 1] + sL[cb + 1];
        v.z = v.z * aL[cb + 2] + sL[cb + 2];
        v.w = v.w * aL[cb + 3] + sL[cb + 3];
        *(float4*)&out[i * 4] = v;
    }
}

extern "C" void kernel_launch(void* const* d_in, const int* in_sizes, int n_in,
                              void* d_out, int out_size, void* d_ws, size_t ws_size,
                              hipStream_t stream)
{
    (void)in_sizes; (void)n_in; (void)out_size; (void)ws_size;
    const float* x          = (const float*)d_in[0];
    const float* Wqkv       = (const float*)d_in[1];
    const float* g1         = (const float*)d_in[2];
    const float* b1         = (const float*)d_in[3];
    const float* bias_table = (const float*)d_in[4];
    const float* Wproj      = (const float*)d_in[5];
    const float* g2         = (const float*)d_in[6];
    const float* b2         = (const float*)d_in[7];
    const int*   idxs       = (const int*)d_in[8];
    float*       out        = (float*)d_out;

    char* ws = (char*)d_ws;
    f16* hbuf = (f16*)ws;                                 // [0, 154,140,672)
    f16* obuf = (f16*)(ws + 154140672LL);                 // [154,140,672, 256,901,120)
    f16* xh   = (f16*)(ws + 154140672LL);                 // overlay (dead before attn)
    f16* wqh  = (f16*)(ws + 154140672LL + 25690112LL);
    f16* wph  = (f16*)ws;                                 // overlay hbuf (dead after attn)
    float* stats = (float*)(ws + 256901120LL);
    float* gsum1 = stats;            float* gsq1 = stats + 1536;
    float* gsum2 = stats + 3072;     float* gsq2 = stats + 3328;
    float* a1 = stats + 3584;        float* s1 = a1 + 1536;
    float* a2 = s1 + 1536;           float* s2 = a2 + 256;
    f16* bias_full = (f16*)(ws + 256901120LL + 65536LL);  // 8*208*224*2 = 745,472 B

    hipMemsetAsync(stats, 0, 3584 * sizeof(float), stream);

    cvt_f32_f16<<<12544, 256, 0, stream>>>(x, xh, 3211264);
    cvt_f32_f16<<<384,   256, 0, stream>>>(Wqkv, wqh, 98304);
    build_bias<<<1456, 256, 0, stream>>>(bias_table, idxs, bias_full);

    gemm1_qkv<<<dim3(392, 12), 256, 0, stream>>>(xh, wqh, hbuf, gsum1, gsq1);
    bn_fin<<<6, 256, 0, stream>>>(gsum1, gsq1, g1, b1, a1, s1, 1536);

    attn_kernel<<<2048, 832, 0, stream>>>(hbuf, a1, s1, bias_full, obuf);

    cvt_f32_f16<<<256, 256, 0, stream>>>(Wproj, wph, 65536);

    gemm2_proj<<<dim3(392, 2), 256, 0, stream>>>(obuf, wph, out, gsum2, gsq2);
    bn_fin<<<1, 256, 0, stream>>>(gsum2, gsq2, g2, b2, a2, s2, 256);

    bn_apply<<<1024, 256, 0, stream>>>(out, a2, s2);
}

// Round 10
// 415.005 us; speedup vs baseline: 1.0835x; 1.0835x over previous
//
#include <hip/hip_runtime.h>

typedef _Float16 f16;
typedef __attribute__((ext_vector_type(8))) _Float16 half8;   // MFMA A/B frag (4 VGPRs)
typedef __attribute__((ext_vector_type(4))) _Float16 half4;
typedef __attribute__((ext_vector_type(4))) float   f4;       // MFMA C/D

#define NTOK   196
#define MROWS  50176            // 256 * 196
#define HIDN   1536
#define HPC    192              // per-head channels in h (q32|k32|v128)
#define DHD    1024             // H * 128
#define EPSV   1e-5f
#define SCALEV 0.17677669529663687f
#define VST    258              // vT row stride (f16): 516 B -> banks shift 1/row

// async global->LDS, 16B per lane; LDS dest is wave-uniform base + lane*16
#define GLD16(gp, lp) __builtin_amdgcn_global_load_lds( \
    (const __attribute__((address_space(1))) unsigned int*)(gp), \
    (__attribute__((address_space(3))) unsigned int*)(lp), 16, 0, 0)

// rotation swizzle for ks only (reads row bits 0-3, writes row bits 3-5)
__device__ inline int swz8(int row) { return (((row & 7) ^ ((row >> 3) & 7))) * 8; }

// ---------------- f32 -> f16 convert (vectorized)
__global__ void cvt_f32_f16(const float* __restrict__ src, f16* __restrict__ dst, int n4)
{
    int i = blockIdx.x * blockDim.x + threadIdx.x;
    if (i < n4) {
        float4 v = *(const float4*)&src[i * 4];
        half4 h = { (f16)v.x, (f16)v.y, (f16)v.z, (f16)v.w };
        *(half4*)&dst[i * 4] = h;
    }
}

// ---------------- bias_full[h][208][224] f16: idxs gather resolved once; pad = -30000 (mask baked in)
__global__ void build_bias(const float* __restrict__ bt, const int* __restrict__ idxs,
                           f16* __restrict__ bf)
{
    int i = blockIdx.x * 256 + threadIdx.x;
    if (i >= 8 * 208 * 224) return;
    int k = i % 224, q = (i / 224) % 208, h = i / (224 * 208);
    float v = -30000.f;
    if (q < NTOK && k < NTOK) v = bt[h * NTOK + idxs[q * NTOK + k]];
    bf[i] = (f16)v;
}

// ---- shared pipeline body for both GEMMs ----
// Race-freedom: (a) lgkmcnt(0) after ds_reads, before next body's s_barrier ->
// reads complete before any wave passes it; (b) GLD overwriting buf[(ST+2)%3]
// issues AFTER that barrier; (c) vmcnt(4) at body top: step ST's group retired
// (in-order), only the newest 4 outstanding. Distinct named buffers keep alias
// analysis exact (v6 lesson). setprio around the MFMA cluster (m218b).
#define PIPE_BODY(CA, CB, PA, PB, ST, HASPF, GATE)                              \
  {                                                                             \
    asm volatile("s_waitcnt vmcnt(" GATE ")" ::: "memory");                     \
    __builtin_amdgcn_s_barrier();                                               \
    __builtin_amdgcn_sched_barrier(0);                                          \
    if (HASPF) {                                                                \
      const f16* Apf_ = Ab + ((ST) + 2) * 32;                                   \
      const f16* Bpf_ = Bb + ((ST) + 2) * 32;                                   \
      GLD16(Apf_,          &PA[so0]);                                           \
      GLD16(Apf_ + 16 * K, &PA[so1]);                                           \
      GLD16(Bpf_,          &PB[so0]);                                           \
      GLD16(Bpf_ + 16 * K, &PB[so1]);                                           \
    }                                                                           \
    half8 a_[4], b_[4];                                                         \
    _Pragma("unroll")                                                           \
    for (int i_ = 0; i_ < 4; ++i_) {                                            \
      a_[i_] = *(const half8*)&CA[(wm + i_ * 16 + lm) * 32 + rs];               \
      b_[i_] = *(const half8*)&CB[(wn + i_ * 16 + lm) * 32 + rs];               \
    }                                                                           \
    asm volatile("s_waitcnt lgkmcnt(0)" ::: "memory");                          \
    __builtin_amdgcn_sched_barrier(0);                                          \
    __builtin_amdgcn_s_setprio(1);                                              \
    _Pragma("unroll")                                                           \
    for (int i_ = 0; i_ < 4; ++i_)                                              \
      _Pragma("unroll")                                                         \
      for (int j_ = 0; j_ < 4; ++j_)                                            \
        acc[i_][j_] = __builtin_amdgcn_mfma_f32_16x16x32_f16(                   \
            a_[i_], b_[j_], acc[i_][j_], 0, 0, 0);                              \
    __builtin_amdgcn_s_setprio(0);                                              \
  }

// ---------------- GEMM1: h = x @ Wqkv^T  (f16 in, f16 out + BN stats)
__global__ __launch_bounds__(256) void gemm1_qkv(
    const f16* __restrict__ A, const f16* __restrict__ B,
    f16* __restrict__ C, float* __restrict__ gsum, float* __restrict__ gsq)
{
    const int K = 256, ldc = HIDN;
    __shared__ f16 As0[4096], As1[4096], As2[4096];
    __shared__ f16 Bs0[4096], Bs1[4096], Bs2[4096];
    __shared__ float ssum[128], ssq[128];

    const int t = threadIdx.x;
    const int m0 = blockIdx.x * 128, n0 = blockIdx.y * 128;
    const int wid = t >> 6, lane = t & 63, quad = lane >> 4, lm = lane & 15;
    const int wm = (wid >> 1) * 64, wn = (wid & 1) * 64;

    const int lr = lane >> 2;
    const int lc = ((lane & 3) ^ (lr & 3)) * 8;        // staging source pre-swizzle
    const int so0 = (wid * 2 + 0) * 512, so1 = (wid * 2 + 1) * 512;
    const f16* Ab = A + (long)(m0 + wid * 32 + lr) * K + lc;
    const f16* Bb = B + (long)(n0 + wid * 32 + lr) * K + lc;
    const int rs = (quad ^ (lm & 3)) * 8;              // matching read-side XOR

    f4 acc[4][4] = {};

    GLD16(Ab,               &As0[so0]);
    GLD16(Ab + 16 * K,      &As0[so1]);
    GLD16(Bb,               &Bs0[so0]);
    GLD16(Bb + 16 * K,      &Bs0[so1]);
    GLD16(Ab + 32,          &As1[so0]);
    GLD16(Ab + 16 * K + 32, &As1[so1]);
    GLD16(Bb + 32,          &Bs1[so0]);
    GLD16(Bb + 16 * K + 32, &Bs1[so1]);

    PIPE_BODY(As0, Bs0, As2, Bs2, 0, 1, "4");
    PIPE_BODY(As1, Bs1, As0, Bs0, 1, 1, "4");
    PIPE_BODY(As2, Bs2, As1, Bs1, 2, 1, "4");
    PIPE_BODY(As0, Bs0, As2, Bs2, 3, 1, "4");
    PIPE_BODY(As1, Bs1, As0, Bs0, 4, 1, "4");
    PIPE_BODY(As2, Bs2, As1, Bs1, 5, 1, "4");
    PIPE_BODY(As0, Bs0, As2, Bs2, 6, 0, "4");
    PIPE_BODY(As1, Bs1, As0, Bs0, 7, 0, "0");

    __syncthreads();
    if (t < 128) { ssum[t] = 0.f; ssq[t] = 0.f; }
    __syncthreads();

    #pragma unroll
    for (int j = 0; j < 4; ++j) {
        int nl = wn + j*16 + lm;
        float psum = 0.f, psq = 0.f;
        #pragma unroll
        for (int i = 0; i < 4; ++i) {
            #pragma unroll
            for (int r = 0; r < 4; ++r) {
                int ml = wm + i*16 + quad*4 + r;
                float v = acc[i][j][r];
                f16 uh = (f16)v;
                float vb = (float)uh;
                C[(long)(m0 + ml) * ldc + n0 + nl] = uh;
                psum += vb; psq += vb * vb;
            }
        }
        atomicAdd(&ssum[nl], psum);
        atomicAdd(&ssq[nl], psq);
    }
    __syncthreads();
    if (t < 128) {
        atomicAdd(&gsum[n0 + t], ssum[t]);
        atomicAdd(&gsq[n0 + t],  ssq[t]);
    }
}

// ---------------- GEMM2: p = o @ Wproj^T  (f16 in, f32 out + BN stats)
__global__ __launch_bounds__(256) void gemm2_proj(
    const f16* __restrict__ A, const f16* __restrict__ B,
    float* __restrict__ C, float* __restrict__ gsum, float* __restrict__ gsq)
{
    const int K = 1024, ldc = 256;
    __shared__ f16 As0[4096], As1[4096], As2[4096];
    __shared__ f16 Bs0[4096], Bs1[4096], Bs2[4096];
    __shared__ float ssum[128], ssq[128];

    const int t = threadIdx.x;
    const int m0 = blockIdx.x * 128, n0 = blockIdx.y * 128;
    const int wid = t >> 6, lane = t & 63, quad = lane >> 4, lm = lane & 15;
    const int wm = (wid >> 1) * 64, wn = (wid & 1) * 64;

    const int lr = lane >> 2;
    const int lc = ((lane & 3) ^ (lr & 3)) * 8;
    const int so0 = (wid * 2 + 0) * 512, so1 = (wid * 2 + 1) * 512;
    const f16* Ab = A + (long)(m0 + wid * 32 + lr) * K + lc;
    const f16* Bb = B + (long)(n0 + wid * 32 + lr) * K + lc;
    const int rs = (quad ^ (lm & 3)) * 8;

    f4 acc[4][4] = {};

    GLD16(Ab,               &As0[so0]);
    GLD16(Ab + 16 * K,      &As0[so1]);
    GLD16(Bb,               &Bs0[so0]);
    GLD16(Bb + 16 * K,      &Bs0[so1]);
    GLD16(Ab + 32,          &As1[so0]);
    GLD16(Ab + 16 * K + 32, &As1[so1]);
    GLD16(Bb + 32,          &Bs1[so0]);
    GLD16(Bb + 16 * K + 32, &Bs1[so1]);

    for (int s = 0; s < 30; s += 6) {
        PIPE_BODY(As0, Bs0, As2, Bs2, s + 0, 1, "4");
        PIPE_BODY(As1, Bs1, As0, Bs0, s + 1, 1, "4");
        PIPE_BODY(As2, Bs2, As1, Bs1, s + 2, 1, "4");
        PIPE_BODY(As0, Bs0, As2, Bs2, s + 3, 1, "4");
        PIPE_BODY(As1, Bs1, As0, Bs0, s + 4, 1, "4");
        PIPE_BODY(As2, Bs2, As1, Bs1, s + 5, 1, "4");
    }
    PIPE_BODY(As0, Bs0, As2, Bs2, 30, 0, "4");
    PIPE_BODY(As1, Bs1, As0, Bs0, 31, 0, "0");

    __syncthreads();
    if (t < 128) { ssum[t] = 0.f; ssq[t] = 0.f; }
    __syncthreads();

    #pragma unroll
    for (int j = 0; j < 4; ++j) {
        int nl = wn + j*16 + lm;
        float psum = 0.f, psq = 0.f;
        #pragma unroll
        for (int i = 0; i < 4; ++i) {
            #pragma unroll
            for (int r = 0; r < 4; ++r) {
                int ml = wm + i*16 + quad*4 + r;
                float v = acc[i][j][r];
                C[(long)(m0 + ml) * ldc + n0 + nl] = v;
                psum += v; psq += v * v;
            }
        }
        atomicAdd(&ssum[nl], psum);
        atomicAdd(&ssq[nl], psq);
    }
    __syncthreads();
    if (t < 128) {
        atomicAdd(&gsum[n0 + t], ssum[t]);
        atomicAdd(&gsq[n0 + t],  ssq[t]);
    }
}

__global__ void bn_fin(const float* __restrict__ gsum, const float* __restrict__ gsq,
                       const float* __restrict__ g, const float* __restrict__ b,
                       float* __restrict__ a_out, float* __restrict__ s_out, int nch)
{
    int c = blockIdx.x * blockDim.x + threadIdx.x;
    if (c >= nch) return;
    float inv  = 1.f / (float)MROWS;
    float mean = gsum[c] * inv;
    float var  = gsq[c] * inv - mean * mean;
    float a    = g[c] * rsqrtf(var + EPSV);
    a_out[c] = a;
    s_out[c] = b[c] - mean * a;
}

// ---------------- attention: one block (13 waves, 832 threads) per (batch, head).
// v12 = v9 softmax/affine (empirical best) + NEW vT layout:
//   flat stride 258 f16 (516 B) -> banks rotate 1/row; token k of channel c at
//   physical col k + (c&3)*16. PV read bank = 9*lm + 2*quad + const (mod 32):
//   9*lm bijective over 16 lanes, quad pairs (q,q+2) collide only at dlm=4
//   -> exactly 2 lanes/bank = conflict-FREE b32 reads, no runtime swizzle.
//   Odd rows are 4B-aligned only -> reads are u32 pairs (ds_read2_b32 with
//   immediate offsets); staging V-writes use compile-time offsets off one base.
__global__ __launch_bounds__(832) void attn_kernel(
    const f16* __restrict__ hbuf, const float* __restrict__ a1, const float* __restrict__ s1,
    const f16* __restrict__ bf, f16* __restrict__ obuf)
{
    __shared__ f16   ks[208][32];
    __shared__ f16   vTf[128 * VST];      // 66,048 B
    __shared__ float af[192], sf[192];

    const int t  = threadIdx.x;
    const int bb = blockIdx.x >> 3;
    const int hh = blockIdx.x & 7;
    const int wid = t >> 6, lane = t & 63, quad = lane >> 4, lm = lane & 15;

    if (t < 192) { af[t] = a1[hh * HPC + t]; sf[t] = s1[hh * HPC + t]; }
    // zero vT physical cols 192..255 (covers pad tokens 196..207 for every
    // (c&3)*16 shift; real tokens staged after, overwriting)
    for (int i = t; i < 4096; i += 832) {
        int c = i >> 5, col = 192 + (i & 31) * 2;
        *(unsigned int*)&vTf[c * VST + col] = 0u;
    }
    if (t < 384) ks[196 + (t >> 5)][t & 31] = (f16)0.f;
    __syncthreads();

    // stage k/v (channels 32..191) with BN1 affine
    {
        int t8 = t & 7;
        for (int rr = t >> 3; rr < NTOK; rr += 104) {
            const f16* hrow = hbuf + (long)(bb * NTOK + rr) * HIDN + hh * HPC;
            int sr = swz8(rr);
            #pragma unroll
            for (int cc = 0; cc < 3; ++cc) {
                int cb = 32 + (t8 + cc * 8) * 8;   // 32..216 step 8; skip >=192
                if (cb >= 192) continue;
                half8 raw = *(const half8*)(hrow + cb);
                f16 ov[8];
                #pragma unroll
                for (int e = 0; e < 8; ++e)
                    ov[e] = (f16)((float)raw[e] * af[cb + e] + sf[cb + e]);
                if (cb < 64) {
                    // rotation start (cb-32+sr)&31 is a multiple of 8 -> contiguous
                    half8 kv;
                    #pragma unroll
                    for (int e = 0; e < 8; ++e) kv[e] = ov[e];
                    *(half8*)&ks[rr][(cb - 32 + sr) & 31] = kv;
                } else {
                    // physical col = rr + (c&3)*16, c = cb-64+e -> c&3 = e&3;
                    // per-e offset = e*258 + (e&3)*16, compile-time (ds imm)
                    f16* vp = &vTf[(cb - 64) * VST + rr];
                    vp[0]    = ov[0];
                    vp[274]  = ov[1];
                    vp[548]  = ov[2];
                    vp[822]  = ov[3];
                    vp[1032] = ov[4];
                    vp[1306] = ov[5];
                    vp[1580] = ov[6];
                    vp[1854] = ov[7];
                }
            }
        }
    }
    __syncthreads();

    const int mt = wid;                                  // one tile per wave, 13 waves
    const int qrow = mt * 16 + lm;                       // 0..207 (>=196 masked rows)
    const f16* bfh = bf + hh * 208 * 224;

    // ---- q B-frag direct from global + BN1 affine (q = channels 0..31)
    long grow = (long)bb * NTOK + qrow;
    if (grow > (long)(MROWS - 1)) grow = MROWS - 1;      // clamp tail OOB (values masked)
    half8 qraw = *(const half8*)(hbuf + grow * HIDN + hh * HPC + quad * 8);
    half8 qf;
    #pragma unroll
    for (int e = 0; e < 8; ++e)
        qf[e] = (f16)((float)qraw[e] * af[quad * 8 + e] + sf[quad * 8 + e]);

    // ---- S^T = K·Q^T (13 MFMAs). Lane holds q = qrow (col=lm), k = nt*16 + quad*4 + r.
    f4 sreg[13];
    #pragma unroll
    for (int nt = 0; nt < 13; ++nt) {
        int krow = nt * 16 + lm;
        half8 ak = *(const half8*)&ks[krow][(quad * 8 + swz8(krow)) & 31];
        f4 z = {};
        sreg[nt] = __builtin_amdgcn_mfma_f32_16x16x32_f16(ak, qf, z, 0, 0, 0);
    }

    // ---- scale + bias (mask baked into bias pad rows/cols), running max
    const f16* brow = bfh + qrow * 224 + quad * 4;
    float m = -3.0e38f;
    #pragma unroll
    for (int nt = 0; nt < 13; ++nt) {
        half4 b4 = *(const half4*)(brow + nt * 16);
        #pragma unroll
        for (int r = 0; r < 4; ++r) {
            sreg[nt][r] = fmaf(sreg[nt][r], SCALEV, (float)b4[r]);
            m = fmaxf(m, sreg[nt][r]);
        }
    }
    m = fmaxf(m, __shfl_xor(m, 16));
    m = fmaxf(m, __shfl_xor(m, 32));

    // ---- exp + sum; P stays unnormalized (<=1) f16 in regs as PV A-frags
    float s = 0.f;
    half4 ap[13];
    #pragma unroll
    for (int nt = 0; nt < 13; ++nt) {
        float e0 = __expf(sreg[nt][0] - m);
        float e1 = __expf(sreg[nt][1] - m);
        float e2 = __expf(sreg[nt][2] - m);
        float e3 = __expf(sreg[nt][3] - m);
        s += (e0 + e1) + (e2 + e3);
        ap[nt] = half4{ (f16)e0, (f16)e1, (f16)e2, (f16)e3 };
    }
    s += __shfl_xor(s, 16);
    s += __shfl_xor(s, 32);
    float rinv = 1.f / s;

    // redistribute rinv to output layout (row = quad*4+r)
    float rv[4];
    #pragma unroll
    for (int r = 0; r < 4; ++r) rv[r] = __shfl(rinv, quad * 4 + r);

    // ---- O = P·V via 16x16x16; bv from conflict-free stride-258 layout
    const int vcol0 = quad * 4 + (lm & 3) * 16;          // read shift = (c&3)*16, c&3 == lm&3
    #pragma unroll
    for (int ct = 0; ct < 8; ++ct) {
        int c = ct * 16 + lm;
        const f16* vrow = &vTf[c * VST + vcol0];
        f4 oa = {};
        #pragma unroll
        for (int nt = 0; nt < 13; ++nt) {
            unsigned int w0 = *(const unsigned int*)&vrow[nt * 16];
            unsigned int w1 = *(const unsigned int*)&vrow[nt * 16 + 2];
            unsigned int wp[2] = { w0, w1 };
            half4 bv = *(const half4*)wp;
            oa = __builtin_amdgcn_mfma_f32_16x16x16f16(ap[nt], bv, oa, 0, 0, 0);
        }
        #pragma unroll
        for (int r = 0; r < 4; ++r) {
            int qr = mt * 16 + quad * 4 + r;
            if (qr < 196) {
                float v  = oa[r] * rv[r];
                float hs = v * fminf(fmaxf(v + 3.f, 0.f), 6.f) * (1.f / 6.f);
                obuf[(long)(bb * NTOK + qr) * DHD + hh * 128 + c] = (f16)hs;
            }
        }
    }
}

__global__ __launch_bounds__(256) void bn_apply(
    float* __restrict__ out, const float* __restrict__ a2, const float* __restrict__ s2)
{
    __shared__ float aL[256], sL[256];
    int t = threadIdx.x;
    aL[t] = a2[t]; sL[t] = s2[t];
    __syncthreads();
    long total = (long)MROWS * 256 / 4;
    for (long i = (long)blockIdx.x * 256 + t; i < total; i += (long)gridDim.x * 256) {
        float4 v = *(float4*)&out[i * 4];
        int cb = (int)((i * 4) & 255);
        v.x = v.x * aL[cb + 0] + sL[cb + 0];
        v.y = v.y * aL[cb + 1] + sL[cb + 1];
        v.z = v.z * aL[cb + 2] + sL[cb + 2];
        v.w = v.w * aL[cb + 3] + sL[cb + 3];
        *(float4*)&out[i * 4] = v;
    }
}

extern "C" void kernel_launch(void* const* d_in, const int* in_sizes, int n_in,
                              void* d_out, int out_size, void* d_ws, size_t ws_size,
                              hipStream_t stream)
{
    (void)in_sizes; (void)n_in; (void)out_size; (void)ws_size;
    const float* x          = (const float*)d_in[0];
    const float* Wqkv       = (const float*)d_in[1];
    const float* g1         = (const float*)d_in[2];
    const float* b1         = (const float*)d_in[3];
    const float* bias_table = (const float*)d_in[4];
    const float* Wproj      = (const float*)d_in[5];
    const float* g2         = (const float*)d_in[6];
    const float* b2         = (const float*)d_in[7];
    const int*   idxs       = (const int*)d_in[8];
    float*       out        = (float*)d_out;

    char* ws = (char*)d_ws;
    f16* hbuf = (f16*)ws;                                 // [0, 154,140,672)
    f16* obuf = (f16*)(ws + 154140672LL);                 // [154,140,672, 256,901,120)
    f16* xh   = (f16*)(ws + 154140672LL);                 // overlay (dead before attn)
    f16* wqh  = (f16*)(ws + 154140672LL + 25690112LL);
    f16* wph  = (f16*)ws;                                 // overlay hbuf (dead after attn)
    float* stats = (float*)(ws + 256901120LL);
    float* gsum1 = stats;            float* gsq1 = stats + 1536;
    float* gsum2 = stats + 3072;     float* gsq2 = stats + 3328;
    float* a1 = stats + 3584;        float* s1 = a1 + 1536;
    float* a2 = s1 + 1536;           float* s2 = a2 + 256;
    f16* bias_full = (f16*)(ws + 256901120LL + 65536LL);  // 8*208*224*2 = 745,472 B

    hipMemsetAsync(stats, 0, 3584 * sizeof(float), stream);

    cvt_f32_f16<<<12544, 256, 0, stream>>>(x, xh, 3211264);
    cvt_f32_f16<<<384,   256, 0, stream>>>(Wqkv, wqh, 98304);
    build_bias<<<1456, 256, 0, stream>>>(bias_table, idxs, bias_full);

    gemm1_qkv<<<dim3(392, 12), 256, 0, stream>>>(xh, wqh, hbuf, gsum1, gsq1);
    bn_fin<<<6, 256, 0, stream>>>(gsum1, gsq1, g1, b1, a1, s1, 1536);

    attn_kernel<<<2048, 832, 0, stream>>>(hbuf, a1, s1, bias_full, obuf);

    cvt_f32_f16<<<256, 256, 0, stream>>>(Wproj, wph, 65536);

    gemm2_proj<<<dim3(392, 2), 256, 0, stream>>>(obuf, wph, out, gsum2, gsq2);
    bn_fin<<<1, 256, 0, stream>>>(gsum2, gsq2, g2, b2, a2, s2, 256);

    bn_apply<<<1024, 256, 0, stream>>>(out, a2, s2);
}

// Round 11
// 397.318 us; speedup vs baseline: 1.1317x; 1.0445x over previous
//
#include <hip/hip_runtime.h>

typedef _Float16 f16;
typedef __attribute__((ext_vector_type(8))) _Float16 half8;   // MFMA A/B frag (4 VGPRs)
typedef __attribute__((ext_vector_type(4))) _Float16 half4;
typedef __attribute__((ext_vector_type(4))) float   f4;       // MFMA C/D

#define NTOK   196
#define MROWS  50176            // 256 * 196
#define HIDN   1536
#define HPC    192              // per-head channels in h (q32|k32|v128)
#define DHD    1024             // H * 128
#define EPSV   1e-5f
#define SCALEV 0.17677669529663687f
#define VST    258              // vT row stride (f16): 516 B -> banks shift 1/row

// async global->LDS, 16B per lane; LDS dest is wave-uniform base + lane*16
#define GLD16(gp, lp) __builtin_amdgcn_global_load_lds( \
    (const __attribute__((address_space(1))) unsigned int*)(gp), \
    (__attribute__((address_space(3))) unsigned int*)(lp), 16, 0, 0)

// rotation swizzle for ks only (reads row bits 0-3, writes row bits 3-5)
__device__ inline int swz8(int row) { return (((row & 7) ^ ((row >> 3) & 7))) * 8; }

// ---------------- f32 -> f16 convert (vectorized)
__global__ void cvt_f32_f16(const float* __restrict__ src, f16* __restrict__ dst, int n4)
{
    int i = blockIdx.x * blockDim.x + threadIdx.x;
    if (i < n4) {
        float4 v = *(const float4*)&src[i * 4];
        half4 h = { (f16)v.x, (f16)v.y, (f16)v.z, (f16)v.w };
        *(half4*)&dst[i * 4] = h;
    }
}

// ---------------- bias_full[h][208][224] f16: idxs gather resolved once; pad = -30000 (mask baked in)
__global__ void build_bias(const float* __restrict__ bt, const int* __restrict__ idxs,
                           f16* __restrict__ bf)
{
    int i = blockIdx.x * 256 + threadIdx.x;
    if (i >= 8 * 208 * 224) return;
    int k = i % 224, q = (i / 224) % 208, h = i / (224 * 208);
    float v = -30000.f;
    if (q < NTOK && k < NTOK) v = bt[h * NTOK + idxs[q * NTOK + k]];
    bf[i] = (f16)v;
}

// ---- shared pipeline body for both GEMMs ----
// Race-freedom: (a) lgkmcnt(0) after ds_reads, before next body's s_barrier ->
// reads complete before any wave passes it; (b) GLD overwriting buf[(ST+2)%3]
// issues AFTER that barrier; (c) vmcnt(4) at body top: step ST's group retired
// (in-order), only the newest 4 outstanding. Distinct named buffers keep alias
// analysis exact (v6 lesson). setprio around the MFMA cluster (m218b).
#define PIPE_BODY(CA, CB, PA, PB, ST, HASPF, GATE)                              \
  {                                                                             \
    asm volatile("s_waitcnt vmcnt(" GATE ")" ::: "memory");                     \
    __builtin_amdgcn_s_barrier();                                               \
    __builtin_amdgcn_sched_barrier(0);                                          \
    if (HASPF) {                                                                \
      const f16* Apf_ = Ab + ((ST) + 2) * 32;                                   \
      const f16* Bpf_ = Bb + ((ST) + 2) * 32;                                   \
      GLD16(Apf_,          &PA[so0]);                                           \
      GLD16(Apf_ + 16 * K, &PA[so1]);                                           \
      GLD16(Bpf_,          &PB[so0]);                                           \
      GLD16(Bpf_ + 16 * K, &PB[so1]);                                           \
    }                                                                           \
    half8 a_[4], b_[4];                                                         \
    _Pragma("unroll")                                                           \
    for (int i_ = 0; i_ < 4; ++i_) {                                            \
      a_[i_] = *(const half8*)&CA[(wm + i_ * 16 + lm) * 32 + rs];               \
      b_[i_] = *(const half8*)&CB[(wn + i_ * 16 + lm) * 32 + rs];               \
    }                                                                           \
    asm volatile("s_waitcnt lgkmcnt(0)" ::: "memory");                          \
    __builtin_amdgcn_sched_barrier(0);                                          \
    __builtin_amdgcn_s_setprio(1);                                              \
    _Pragma("unroll")                                                           \
    for (int i_ = 0; i_ < 4; ++i_)                                              \
      _Pragma("unroll")                                                         \
      for (int j_ = 0; j_ < 4; ++j_)                                            \
        acc[i_][j_] = __builtin_amdgcn_mfma_f32_16x16x32_f16(                   \
            a_[i_], b_[j_], acc[i_][j_], 0, 0, 0);                              \
    __builtin_amdgcn_s_setprio(0);                                              \
  }

// ---------------- GEMM1: h = x @ Wqkv^T  (f16 in, f16 out + BN stats)
// v13: 1D grid + XCD-chunked bijective remap. 4704 = 8 x 588: XCD k gets 588
// consecutive x-major blocks = 49 m-panels x all 12 n-blocks; its A working set
// (3.2 MB) + whole B (0.8 MB) fit the 4 MB per-XCD L2 -> the 12x A re-reads
// become L2 hits instead of HBM fetches.
__global__ __launch_bounds__(256) void gemm1_qkv(
    const f16* __restrict__ A, const f16* __restrict__ B,
    f16* __restrict__ C, float* __restrict__ gsum, float* __restrict__ gsq)
{
    const int K = 256, ldc = HIDN;
    __shared__ f16 As0[4096], As1[4096], As2[4096];
    __shared__ f16 Bs0[4096], Bs1[4096], Bs2[4096];
    __shared__ float ssum[128], ssq[128];

    const int t = threadIdx.x;
    const int b = blockIdx.x;
    const int sw = (b & 7) * 588 + (b >> 3);           // bijective: 4704 = 8*588
    const int m0 = (sw / 12) * 128, n0 = (sw % 12) * 128;
    const int wid = t >> 6, lane = t & 63, quad = lane >> 4, lm = lane & 15;
    const int wm = (wid >> 1) * 64, wn = (wid & 1) * 64;

    const int lr = lane >> 2;
    const int lc = ((lane & 3) ^ (lr & 3)) * 8;        // staging source pre-swizzle
    const int so0 = (wid * 2 + 0) * 512, so1 = (wid * 2 + 1) * 512;
    const f16* Ab = A + (long)(m0 + wid * 32 + lr) * K + lc;
    const f16* Bb = B + (long)(n0 + wid * 32 + lr) * K + lc;
    const int rs = (quad ^ (lm & 3)) * 8;              // matching read-side XOR

    f4 acc[4][4] = {};

    GLD16(Ab,               &As0[so0]);
    GLD16(Ab + 16 * K,      &As0[so1]);
    GLD16(Bb,               &Bs0[so0]);
    GLD16(Bb + 16 * K,      &Bs0[so1]);
    GLD16(Ab + 32,          &As1[so0]);
    GLD16(Ab + 16 * K + 32, &As1[so1]);
    GLD16(Bb + 32,          &Bs1[so0]);
    GLD16(Bb + 16 * K + 32, &Bs1[so1]);

    PIPE_BODY(As0, Bs0, As2, Bs2, 0, 1, "4");
    PIPE_BODY(As1, Bs1, As0, Bs0, 1, 1, "4");
    PIPE_BODY(As2, Bs2, As1, Bs1, 2, 1, "4");
    PIPE_BODY(As0, Bs0, As2, Bs2, 3, 1, "4");
    PIPE_BODY(As1, Bs1, As0, Bs0, 4, 1, "4");
    PIPE_BODY(As2, Bs2, As1, Bs1, 5, 1, "4");
    PIPE_BODY(As0, Bs0, As2, Bs2, 6, 0, "4");
    PIPE_BODY(As1, Bs1, As0, Bs0, 7, 0, "0");

    __syncthreads();
    if (t < 128) { ssum[t] = 0.f; ssq[t] = 0.f; }
    __syncthreads();

    #pragma unroll
    for (int j = 0; j < 4; ++j) {
        int nl = wn + j*16 + lm;
        float psum = 0.f, psq = 0.f;
        #pragma unroll
        for (int i = 0; i < 4; ++i) {
            #pragma unroll
            for (int r = 0; r < 4; ++r) {
                int ml = wm + i*16 + quad*4 + r;
                float v = acc[i][j][r];
                f16 uh = (f16)v;
                float vb = (float)uh;
                C[(long)(m0 + ml) * ldc + n0 + nl] = uh;
                psum += vb; psq += vb * vb;
            }
        }
        atomicAdd(&ssum[nl], psum);
        atomicAdd(&ssq[nl], psq);
    }
    __syncthreads();
    if (t < 128) {
        atomicAdd(&gsum[n0 + t], ssum[t]);
        atomicAdd(&gsq[n0 + t],  ssq[t]);
    }
}

// ---------------- GEMM2: p = o @ Wproj^T  (f16 in, f32 out + BN stats)
// v13: same XCD-chunked remap (784 = 8 x 98); the 2 n-blocks sharing an A-tile
// land consecutively on one XCD -> second read is an L2 hit.
__global__ __launch_bounds__(256) void gemm2_proj(
    const f16* __restrict__ A, const f16* __restrict__ B,
    float* __restrict__ C, float* __restrict__ gsum, float* __restrict__ gsq)
{
    const int K = 1024, ldc = 256;
    __shared__ f16 As0[4096], As1[4096], As2[4096];
    __shared__ f16 Bs0[4096], Bs1[4096], Bs2[4096];
    __shared__ float ssum[128], ssq[128];

    const int t = threadIdx.x;
    const int b = blockIdx.x;
    const int sw = (b & 7) * 98 + (b >> 3);            // bijective: 784 = 8*98
    const int m0 = (sw >> 1) * 128, n0 = (sw & 1) * 128;
    const int wid = t >> 6, lane = t & 63, quad = lane >> 4, lm = lane & 15;
    const int wm = (wid >> 1) * 64, wn = (wid & 1) * 64;

    const int lr = lane >> 2;
    const int lc = ((lane & 3) ^ (lr & 3)) * 8;
    const int so0 = (wid * 2 + 0) * 512, so1 = (wid * 2 + 1) * 512;
    const f16* Ab = A + (long)(m0 + wid * 32 + lr) * K + lc;
    const f16* Bb = B + (long)(n0 + wid * 32 + lr) * K + lc;
    const int rs = (quad ^ (lm & 3)) * 8;

    f4 acc[4][4] = {};

    GLD16(Ab,               &As0[so0]);
    GLD16(Ab + 16 * K,      &As0[so1]);
    GLD16(Bb,               &Bs0[so0]);
    GLD16(Bb + 16 * K,      &Bs0[so1]);
    GLD16(Ab + 32,          &As1[so0]);
    GLD16(Ab + 16 * K + 32, &As1[so1]);
    GLD16(Bb + 32,          &Bs1[so0]);
    GLD16(Bb + 16 * K + 32, &Bs1[so1]);

    for (int s = 0; s < 30; s += 6) {
        PIPE_BODY(As0, Bs0, As2, Bs2, s + 0, 1, "4");
        PIPE_BODY(As1, Bs1, As0, Bs0, s + 1, 1, "4");
        PIPE_BODY(As2, Bs2, As1, Bs1, s + 2, 1, "4");
        PIPE_BODY(As0, Bs0, As2, Bs2, s + 3, 1, "4");
        PIPE_BODY(As1, Bs1, As0, Bs0, s + 4, 1, "4");
        PIPE_BODY(As2, Bs2, As1, Bs1, s + 5, 1, "4");
    }
    PIPE_BODY(As0, Bs0, As2, Bs2, 30, 0, "4");
    PIPE_BODY(As1, Bs1, As0, Bs0, 31, 0, "0");

    __syncthreads();
    if (t < 128) { ssum[t] = 0.f; ssq[t] = 0.f; }
    __syncthreads();

    #pragma unroll
    for (int j = 0; j < 4; ++j) {
        int nl = wn + j*16 + lm;
        float psum = 0.f, psq = 0.f;
        #pragma unroll
        for (int i = 0; i < 4; ++i) {
            #pragma unroll
            for (int r = 0; r < 4; ++r) {
                int ml = wm + i*16 + quad*4 + r;
                float v = acc[i][j][r];
                C[(long)(m0 + ml) * ldc + n0 + nl] = v;
                psum += v; psq += v * v;
            }
        }
        atomicAdd(&ssum[nl], psum);
        atomicAdd(&ssq[nl], psq);
    }
    __syncthreads();
    if (t < 128) {
        atomicAdd(&gsum[n0 + t], ssum[t]);
        atomicAdd(&gsq[n0 + t],  ssq[t]);
    }
}

__global__ void bn_fin(const float* __restrict__ gsum, const float* __restrict__ gsq,
                       const float* __restrict__ g, const float* __restrict__ b,
                       float* __restrict__ a_out, float* __restrict__ s_out, int nch)
{
    int c = blockIdx.x * blockDim.x + threadIdx.x;
    if (c >= nch) return;
    float inv  = 1.f / (float)MROWS;
    float mean = gsum[c] * inv;
    float var  = gsq[c] * inv - mean * mean;
    float a    = g[c] * rsqrtf(var + EPSV);
    a_out[c] = a;
    s_out[c] = b[c] - mean * a;
}

// ---------------- attention: one block (13 waves, 832 threads) per (batch, head).
// v12 (unchanged): v9 softmax/affine + stride-258 conflict-free vT layout.
__global__ __launch_bounds__(832) void attn_kernel(
    const f16* __restrict__ hbuf, const float* __restrict__ a1, const float* __restrict__ s1,
    const f16* __restrict__ bf, f16* __restrict__ obuf)
{
    __shared__ f16   ks[208][32];
    __shared__ f16   vTf[128 * VST];      // 66,048 B
    __shared__ float af[192], sf[192];

    const int t  = threadIdx.x;
    const int bb = blockIdx.x >> 3;
    const int hh = blockIdx.x & 7;
    const int wid = t >> 6, lane = t & 63, quad = lane >> 4, lm = lane & 15;

    if (t < 192) { af[t] = a1[hh * HPC + t]; sf[t] = s1[hh * HPC + t]; }
    // zero vT physical cols 192..255 (covers pad tokens 196..207 for every
    // (c&3)*16 shift; real tokens staged after, overwriting)
    for (int i = t; i < 4096; i += 832) {
        int c = i >> 5, col = 192 + (i & 31) * 2;
        *(unsigned int*)&vTf[c * VST + col] = 0u;
    }
    if (t < 384) ks[196 + (t >> 5)][t & 31] = (f16)0.f;
    __syncthreads();

    // stage k/v (channels 32..191) with BN1 affine
    {
        int t8 = t & 7;
        for (int rr = t >> 3; rr < NTOK; rr += 104) {
            const f16* hrow = hbuf + (long)(bb * NTOK + rr) * HIDN + hh * HPC;
            int sr = swz8(rr);
            #pragma unroll
            for (int cc = 0; cc < 3; ++cc) {
                int cb = 32 + (t8 + cc * 8) * 8;   // 32..216 step 8; skip >=192
                if (cb >= 192) continue;
                half8 raw = *(const half8*)(hrow + cb);
                f16 ov[8];
                #pragma unroll
                for (int e = 0; e < 8; ++e)
                    ov[e] = (f16)((float)raw[e] * af[cb + e] + sf[cb + e]);
                if (cb < 64) {
                    // rotation start (cb-32+sr)&31 is a multiple of 8 -> contiguous
                    half8 kv;
                    #pragma unroll
                    for (int e = 0; e < 8; ++e) kv[e] = ov[e];
                    *(half8*)&ks[rr][(cb - 32 + sr) & 31] = kv;
                } else {
                    // physical col = rr + (c&3)*16, c = cb-64+e -> c&3 = e&3;
                    // per-e offset = e*258 + (e&3)*16, compile-time (ds imm)
                    f16* vp = &vTf[(cb - 64) * VST + rr];
                    vp[0]    = ov[0];
                    vp[274]  = ov[1];
                    vp[548]  = ov[2];
                    vp[822]  = ov[3];
                    vp[1032] = ov[4];
                    vp[1306] = ov[5];
                    vp[1580] = ov[6];
                    vp[1854] = ov[7];
                }
            }
        }
    }
    __syncthreads();

    const int mt = wid;                                  // one tile per wave, 13 waves
    const int qrow = mt * 16 + lm;                       // 0..207 (>=196 masked rows)
    const f16* bfh = bf + hh * 208 * 224;

    // ---- q B-frag direct from global + BN1 affine (q = channels 0..31)
    long grow = (long)bb * NTOK + qrow;
    if (grow > (long)(MROWS - 1)) grow = MROWS - 1;      // clamp tail OOB (values masked)
    half8 qraw = *(const half8*)(hbuf + grow * HIDN + hh * HPC + quad * 8);
    half8 qf;
    #pragma unroll
    for (int e = 0; e < 8; ++e)
        qf[e] = (f16)((float)qraw[e] * af[quad * 8 + e] + sf[quad * 8 + e]);

    // ---- S^T = K·Q^T (13 MFMAs). Lane holds q = qrow (col=lm), k = nt*16 + quad*4 + r.
    f4 sreg[13];
    #pragma unroll
    for (int nt = 0; nt < 13; ++nt) {
        int krow = nt * 16 + lm;
        half8 ak = *(const half8*)&ks[krow][(quad * 8 + swz8(krow)) & 31];
        f4 z = {};
        sreg[nt] = __builtin_amdgcn_mfma_f32_16x16x32_f16(ak, qf, z, 0, 0, 0);
    }

    // ---- scale + bias (mask baked into bias pad rows/cols), running max
    const f16* brow = bfh + qrow * 224 + quad * 4;
    float m = -3.0e38f;
    #pragma unroll
    for (int nt = 0; nt < 13; ++nt) {
        half4 b4 = *(const half4*)(brow + nt * 16);
        #pragma unroll
        for (int r = 0; r < 4; ++r) {
            sreg[nt][r] = fmaf(sreg[nt][r], SCALEV, (float)b4[r]);
            m = fmaxf(m, sreg[nt][r]);
        }
    }
    m = fmaxf(m, __shfl_xor(m, 16));
    m = fmaxf(m, __shfl_xor(m, 32));

    // ---- exp + sum; P stays unnormalized (<=1) f16 in regs as PV A-frags
    float s = 0.f;
    half4 ap[13];
    #pragma unroll
    for (int nt = 0; nt < 13; ++nt) {
        float e0 = __expf(sreg[nt][0] - m);
        float e1 = __expf(sreg[nt][1] - m);
        float e2 = __expf(sreg[nt][2] - m);
        float e3 = __expf(sreg[nt][3] - m);
        s += (e0 + e1) + (e2 + e3);
        ap[nt] = half4{ (f16)e0, (f16)e1, (f16)e2, (f16)e3 };
    }
    s += __shfl_xor(s, 16);
    s += __shfl_xor(s, 32);
    float rinv = 1.f / s;

    // redistribute rinv to output layout (row = quad*4+r)
    float rv[4];
    #pragma unroll
    for (int r = 0; r < 4; ++r) rv[r] = __shfl(rinv, quad * 4 + r);

    // ---- O = P·V via 16x16x16; bv from conflict-free stride-258 layout
    const int vcol0 = quad * 4 + (lm & 3) * 16;          // read shift = (c&3)*16, c&3 == lm&3
    #pragma unroll
    for (int ct = 0; ct < 8; ++ct) {
        int c = ct * 16 + lm;
        const f16* vrow = &vTf[c * VST + vcol0];
        f4 oa = {};
        #pragma unroll
        for (int nt = 0; nt < 13; ++nt) {
            unsigned int w0 = *(const unsigned int*)&vrow[nt * 16];
            unsigned int w1 = *(const unsigned int*)&vrow[nt * 16 + 2];
            unsigned int wp[2] = { w0, w1 };
            half4 bv = *(const half4*)wp;
            oa = __builtin_amdgcn_mfma_f32_16x16x16f16(ap[nt], bv, oa, 0, 0, 0);
        }
        #pragma unroll
        for (int r = 0; r < 4; ++r) {
            int qr = mt * 16 + quad * 4 + r;
            if (qr < 196) {
                float v  = oa[r] * rv[r];
                float hs = v * fminf(fmaxf(v + 3.f, 0.f), 6.f) * (1.f / 6.f);
                obuf[(long)(bb * NTOK + qr) * DHD + hh * 128 + c] = (f16)hs;
            }
        }
    }
}

__global__ __launch_bounds__(256) void bn_apply(
    float* __restrict__ out, const float* __restrict__ a2, const float* __restrict__ s2)
{
    __shared__ float aL[256], sL[256];
    int t = threadIdx.x;
    aL[t] = a2[t]; sL[t] = s2[t];
    __syncthreads();
    long total = (long)MROWS * 256 / 4;
    for (long i = (long)blockIdx.x * 256 + t; i < total; i += (long)gridDim.x * 256) {
        float4 v = *(float4*)&out[i * 4];
        int cb = (int)((i * 4) & 255);
        v.x = v.x * aL[cb + 0] + sL[cb + 0];
        v.y = v.y * aL[cb + 1] + sL[cb + 1];
        v.z = v.z * aL[cb + 2] + sL[cb + 2];
        v.w = v.w * aL[cb + 3] + sL[cb + 3];
        *(float4*)&out[i * 4] = v;
    }
}

extern "C" void kernel_launch(void* const* d_in, const int* in_sizes, int n_in,
                              void* d_out, int out_size, void* d_ws, size_t ws_size,
                              hipStream_t stream)
{
    (void)in_sizes; (void)n_in; (void)out_size; (void)ws_size;
    const float* x          = (const float*)d_in[0];
    const float* Wqkv       = (const float*)d_in[1];
    const float* g1         = (const float*)d_in[2];
    const float* b1         = (const float*)d_in[3];
    const float* bias_table = (const float*)d_in[4];
    const float* Wproj      = (const float*)d_in[5];
    const float* g2         = (const float*)d_in[6];
    const float* b2         = (const float*)d_in[7];
    const int*   idxs       = (const int*)d_in[8];
    float*       out        = (float*)d_out;

    char* ws = (char*)d_ws;
    f16* hbuf = (f16*)ws;                                 // [0, 154,140,672)
    f16* obuf = (f16*)(ws + 154140672LL);                 // [154,140,672, 256,901,120)
    f16* xh   = (f16*)(ws + 154140672LL);                 // overlay (dead before attn)
    f16* wqh  = (f16*)(ws + 154140672LL + 25690112LL);
    f16* wph  = (f16*)ws;                                 // overlay hbuf (dead after attn)
    float* stats = (float*)(ws + 256901120LL);
    float* gsum1 = stats;            float* gsq1 = stats + 1536;
    float* gsum2 = stats + 3072;     float* gsq2 = stats + 3328;
    float* a1 = stats + 3584;        float* s1 = a1 + 1536;
    float* a2 = s1 + 1536;           float* s2 = a2 + 256;
    f16* bias_full = (f16*)(ws + 256901120LL + 65536LL);  // 8*208*224*2 = 745,472 B

    hipMemsetAsync(stats, 0, 3584 * sizeof(float), stream);

    cvt_f32_f16<<<12544, 256, 0, stream>>>(x, xh, 3211264);
    cvt_f32_f16<<<384,   256, 0, stream>>>(Wqkv, wqh, 98304);
    build_bias<<<1456, 256, 0, stream>>>(bias_table, idxs, bias_full);

    gemm1_qkv<<<4704, 256, 0, stream>>>(xh, wqh, hbuf, gsum1, gsq1);
    bn_fin<<<6, 256, 0, stream>>>(gsum1, gsq1, g1, b1, a1, s1, 1536);

    attn_kernel<<<2048, 832, 0, stream>>>(hbuf, a1, s1, bias_full, obuf);

    cvt_f32_f16<<<256, 256, 0, stream>>>(Wproj, wph, 65536);

    gemm2_proj<<<784, 256, 0, stream>>>(obuf, wph, out, gsum2, gsq2);
    bn_fin<<<1, 256, 0, stream>>>(gsum2, gsq2, g2, b2, a2, s2, 256);

    bn_apply<<<1024, 256, 0, stream>>>(out, a2, s2);
}